// Round 16
// baseline (189.731 us; speedup 1.0000x reference)
//
#include <hip/hip_runtime.h>
#include <hip/hip_bf16.h>
#include <math.h>

#define S_LEN 2048
#define HID   1024
#define NHEAD 16

using bf16x8 = __attribute__((ext_vector_type(8))) short;
using bf16x4 = __attribute__((ext_vector_type(4))) short;
using f32x4  = __attribute__((ext_vector_type(4))) float;

__device__ __forceinline__ float bf2f(short s) {
  union { unsigned u; float f; } c;
  c.u = ((unsigned)(unsigned short)s) << 16;
  return c.f;
}
__device__ __forceinline__ short f2bf(float f) {
  union { float f; unsigned u; } c; c.f = f;
  unsigned u = c.u;
  unsigned r = (u + 0x7fffu + ((u >> 16) & 1u)) >> 16;
  return (short)r;
}
// Self-detect: is x packed bf16 (1) or fp32 storage (0)? 64 uniform words.
__device__ __forceinline__ int detect_bf(const unsigned* xw) {
  int cnt = 0;
#pragma unroll
  for (int i = 0; i < 64; ++i) {
    const unsigned fld = (xw[i] >> 7) & 0xFFu;
    cnt += (fld >= 100u && fld <= 135u) ? 1 : 0;
  }
  return cnt >= 32;
}

// Convert x + 4 weights + 4 biases + cmw to bf16 (self-detecting dtype).
// blockIdx.y: 0=x(2M), 1..4=W(1M), 5..8=bias(1024), 9=cmw(9).
__global__ __launch_bounds__(256) void convert10(
    const void* __restrict__ s0, const void* __restrict__ s1, const void* __restrict__ s2,
    const void* __restrict__ s3, const void* __restrict__ s4, const void* __restrict__ s5,
    const void* __restrict__ s6, const void* __restrict__ s7, const void* __restrict__ s8,
    const void* __restrict__ s9,
    short* __restrict__ d0, short* __restrict__ d1, short* __restrict__ d2,
    short* __restrict__ d3, short* __restrict__ d4, short* __restrict__ d5,
    short* __restrict__ d6, short* __restrict__ d7, short* __restrict__ d8,
    short* __restrict__ d9)
{
  const int is_bf = detect_bf((const unsigned*)s0);
  const int a = blockIdx.y;
  const void* src; short* dst; long n;
  if      (a == 0) { src = s0; dst = d0; n = 2L << 20; }
  else if (a == 1) { src = s1; dst = d1; n = 1L << 20; }
  else if (a == 2) { src = s2; dst = d2; n = 1L << 20; }
  else if (a == 3) { src = s3; dst = d3; n = 1L << 20; }
  else if (a == 4) { src = s4; dst = d4; n = 1L << 20; }
  else if (a == 5) { src = s5; dst = d5; n = 1024; }
  else if (a == 6) { src = s6; dst = d6; n = 1024; }
  else if (a == 7) { src = s7; dst = d7; n = 1024; }
  else if (a == 8) { src = s8; dst = d8; n = 1024; }
  else             { src = s9; dst = d9; n = 9; }

  if (n >= 1024) {
    long i = (long)(blockIdx.x * 256 + threadIdx.x) * 8;
    const long stride = (long)gridDim.x * 256 * 8;
    if (is_bf) {
      for (; i < n; i += stride)
        *(bf16x8*)(dst + i) = *(const bf16x8*)((const short*)src + i);
    } else {
      for (; i < n; i += stride) {
        const float* p = (const float*)src + i;
        bf16x8 r;
#pragma unroll
        for (int j = 0; j < 8; ++j) r[j] = f2bf(p[j]);
        *(bf16x8*)(dst + i) = r;
      }
    }
  } else {
    long i = blockIdx.x * 256 + threadIdx.x;
    const long stride = (long)gridDim.x * 256;
    for (; i < n; i += stride)
      dst[i] = is_bf ? ((const short*)src)[i] : f2bf(((const float*)src)[i]);
  }
}

// Pure-bf16 B^T GEMM, BM=128 BN=64 BK=32, R10-style explicit register-prefetch
// staging (loads for kt+1 issued during MFMA of kt -> genuine overlap).
// C[m,n] = A[m,:].W[n,:] + bias[n]; fp32 acc; bf16 out.
__global__ __launch_bounds__(256) void gemm_bt3(
    const short* __restrict__ A,
    const short* __restrict__ W0, const short* __restrict__ W1, const short* __restrict__ W2,
    const short* __restrict__ b0, const short* __restrict__ b1, const short* __restrict__ b2,
    short* __restrict__ C0, short* __restrict__ C1, short* __restrict__ C2,
    int nbn)
{
  constexpr int K = 1024;
  constexpr int N = 1024;
  __shared__ short As[128 * 32];
  __shared__ short Bs[64 * 32];

  const int t = threadIdx.x;
  const int w = t >> 6, lane = t & 63;
  const int l15 = lane & 15, quad = lane >> 4;
  const int wm = w >> 1, wn = w & 1;

  const int mat = blockIdx.x / nbn;
  const int n0 = (blockIdx.x % nbn) * 64;
  const int m0 = blockIdx.y * 128;

  const short* W   = (mat == 0) ? W0 : (mat == 1 ? W1 : W2);
  const short* bia = (mat == 0) ? b0 : (mat == 1 ? b1 : b2);
  short*       C   = (mat == 0) ? C0 : (mat == 1 ? C1 : C2);

  f32x4 acc[4][2];
  for (int mi = 0; mi < 4; ++mi)
    for (int ni = 0; ni < 2; ++ni)
      for (int r = 0; r < 4; ++r) acc[mi][ni][r] = 0.f;

  const int srow = t >> 2;        // 0..63
  const int sch  = (t & 3) * 8;
  const short* Ap = A + (long)(m0 + srow) * K + sch;
  const short* Wp = W + (long)(n0 + srow) * K + sch;

  bf16x8 ra0 = *(const bf16x8*)(Ap);
  bf16x8 ra1 = *(const bf16x8*)(Ap + 64L * K);
  bf16x8 rb0 = *(const bf16x8*)(Wp);

  for (int kt = 0; kt < K / 32; ++kt) {
    __syncthreads();
    *(bf16x8*)&As[(srow)      * 32 + sch] = ra0;
    *(bf16x8*)&As[(srow + 64) * 32 + sch] = ra1;
    *(bf16x8*)&Bs[(srow)      * 32 + sch] = rb0;
    __syncthreads();
    if (kt + 1 < K / 32) {  // prefetch next tile; vmcnt wait lands at next ds_write
      ra0 = *(const bf16x8*)(Ap + (kt + 1) * 32);
      ra1 = *(const bf16x8*)(Ap + (kt + 1) * 32 + 64L * K);
      rb0 = *(const bf16x8*)(Wp + (kt + 1) * 32);
    }
    bf16x8 af[4], bfr[2];
    for (int mi = 0; mi < 4; ++mi)
      af[mi] = *(const bf16x8*)&As[(wm * 64 + mi * 16 + l15) * 32 + quad * 8];
    for (int ni = 0; ni < 2; ++ni)
      bfr[ni] = *(const bf16x8*)&Bs[(wn * 32 + ni * 16 + l15) * 32 + quad * 8];
    for (int mi = 0; mi < 4; ++mi)
      for (int ni = 0; ni < 2; ++ni)
        acc[mi][ni] = __builtin_amdgcn_mfma_f32_16x16x32_bf16(af[mi], bfr[ni], acc[mi][ni], 0, 0, 0);
  }

  for (int ni = 0; ni < 2; ++ni) {
    const int col = n0 + wn * 32 + ni * 16 + l15;
    const float bv = bf2f(bia[col]);
    for (int mi = 0; mi < 4; ++mi) {
      const int row = m0 + wm * 64 + mi * 16 + quad * 4;
      for (int r = 0; r < 4; ++r)
        C[(long)(row + r) * N + col] = f2bf(acc[mi][ni][r] + bv);
    }
  }
}

// Split-K flash attention, max-free softmax, two k-tiles per barrier (R15).
// blockIdx.x in [0,32): pair=x>>1, par=x&1; blockIdx.y=head.
__global__ __launch_bounds__(256) void attn_split(
    const short* __restrict__ Q, const short* __restrict__ Kg, const short* __restrict__ Vg,
    const int* __restrict__ mod, const short* __restrict__ cmw,
    short* __restrict__ PO0, short* __restrict__ PO1,
    float* __restrict__ PL)
{
  __shared__ short Ks[2][64 * 80];
  __shared__ short Vt[2][64 * 80];
  __shared__ short Ps[4 * 16 * 80];
  __shared__ float cm[9];
  __shared__ int mods[2048];

  const int t = threadIdx.x;
  const int w = t >> 6, lane = t & 63;
  const int l15 = lane & 15, quad = lane >> 4;
  const int h = blockIdx.y;
  const int pair = blockIdx.x >> 1;
  const int par  = blockIdx.x & 1;

  int oddbits = 0;
#pragma unroll
  for (int i = 0; i < 64; ++i) oddbits |= mod[2 * i + 1];
  const int m64 = (oddbits == 0) ? 1 : 0;

  if (t < 9) cm[t] = bf2f(cmw[t]);
  for (int i = t; i < 2048; i += 256) mods[i] = mod[i << m64];
  __syncthreads();

  short* POp = (par == 0) ? PO0 : PO1;
  short* Pw = &Ps[w * 16 * 80];
  const int krow = t >> 3, kch = (t & 7) * 8;
  const int vkp = t & 63, vdc = (t >> 6) * 8;

  for (int si = 0; si < 2; ++si) {
    const int strip = (si == 0) ? pair : 31 - pair;
    const int q0 = strip * 64;
    const int nkt = strip + 1;

    const short* qb = Q + (long)(q0 + w * 16 + l15) * HID + h * 64 + quad * 8;
    const bf16x8 aq0 = *(const bf16x8*)qb;
    const bf16x8 aq1 = *(const bf16x8*)(qb + 32);

    int mrow[4];
    for (int r = 0; r < 4; ++r) mrow[r] = mods[q0 + w * 16 + quad * 4 + r];

    float lsum[4];
    f32x4 acc_o[4];
    for (int r = 0; r < 4; ++r) lsum[r] = 0.f;
    for (int ni = 0; ni < 4; ++ni)
      for (int r = 0; r < 4; ++r) acc_o[ni][r] = 0.f;

    bf16x8 rkA[2], rvA[2], rkB[2], rvB[2];
    auto ldtile = [&](int kt_, bf16x8* rk, bf16x8* rv) {
      const long kb = (long)(kt_ * 64) * HID + h * 64;
      rk[0] = *(const bf16x8*)(Kg + kb + (long)krow * HID + kch);
      rk[1] = *(const bf16x8*)(Kg + kb + (long)(krow + 32) * HID + kch);
      rv[0] = *(const bf16x8*)(Vg + kb + (long)vkp * HID + vdc);
      rv[1] = *(const bf16x8*)(Vg + kb + (long)vkp * HID + 32 + vdc);
    };
    auto sttile = [&](int buf, bf16x8* rk, bf16x8* rv) {
      *(bf16x8*)&Ks[buf][krow * 80 + kch] = rk[0];
      *(bf16x8*)&Ks[buf][(krow + 32) * 80 + kch] = rk[1];
#pragma unroll
      for (int j = 0; j < 8; ++j) Vt[buf][(vdc + j) * 80 + vkp] = rv[0][j];
#pragma unroll
      for (int j = 0; j < 8; ++j) Vt[buf][(vdc + 32 + j) * 80 + vkp] = rv[1][j];
    };
    auto tile_compute = [&](int kt_, int buf) {
      f32x4 sc[4];
      for (int nt = 0; nt < 4; ++nt) {
        const bf16x8 kb0 = *(const bf16x8*)&Ks[buf][(nt * 16 + l15) * 80 + quad * 8];
        const bf16x8 kb1 = *(const bf16x8*)&Ks[buf][(nt * 16 + l15) * 80 + 32 + quad * 8];
        f32x4 z;
        for (int r = 0; r < 4; ++r) z[r] = 0.f;
        z = __builtin_amdgcn_mfma_f32_16x16x32_bf16(aq0, kb0, z, 0, 0, 0);
        z = __builtin_amdgcn_mfma_f32_16x16x32_bf16(aq1, kb1, z, 0, 0, 0);
        sc[nt] = z;
      }
      float sv[4][4];
      for (int nt = 0; nt < 4; ++nt) {
        const int mcol = mods[kt_ * 64 + nt * 16 + l15];
        for (int r = 0; r < 4; ++r)
          sv[nt][r] = sc[nt][r] * 0.125f + cm[mrow[r] * 3 + mcol];
      }
      if (kt_ == nkt - 1) {  // diagonal tile: causal mask
        for (int nt = 0; nt < 4; ++nt) {
          const int col = kt_ * 64 + nt * 16 + l15;
          for (int r = 0; r < 4; ++r) {
            const int row = q0 + w * 16 + quad * 4 + r;
            sv[nt][r] = (col <= row) ? sv[nt][r] : -1e30f;
          }
        }
      }
      short pb[4][4];
      for (int nt = 0; nt < 4; ++nt)
        for (int r = 0; r < 4; ++r) {
          const float p = __expf(fminf(sv[nt][r], 60.f));
          lsum[r] += p;
          pb[nt][r] = f2bf(p);
        }
      for (int nt = 0; nt < 4; ++nt)
        for (int r = 0; r < 4; ++r)
          Pw[(quad * 4 + r) * 80 + nt * 16 + l15] = pb[nt][r];
      asm volatile("s_waitcnt lgkmcnt(0)" ::: "memory");  // wave-local ds RAW drain
      for (int kk = 0; kk < 2; ++kk) {
        const bf16x8 ap = *(const bf16x8*)&Pw[l15 * 80 + kk * 32 + quad * 8];
        for (int ni = 0; ni < 4; ++ni) {
          const bf16x8 bv = *(const bf16x8*)&Vt[buf][(ni * 16 + l15) * 80 + kk * 32 + quad * 8];
          acc_o[ni] = __builtin_amdgcn_mfma_f32_16x16x32_bf16(ap, bv, acc_o[ni], 0, 0, 0);
        }
      }
    };

    if (par < nkt)     ldtile(par, rkA, rvA);
    if (par + 2 < nkt) ldtile(par + 2, rkB, rvB);

    for (int kt = par; kt < nkt; kt += 4) {
      const bool has2 = (kt + 2 < nkt);
      __syncthreads();
      sttile(0, rkA, rvA);
      if (has2) sttile(1, rkB, rvB);
      __syncthreads();
      if (kt + 4 < nkt) ldtile(kt + 4, rkA, rvA);
      if (kt + 6 < nkt) ldtile(kt + 6, rkB, rvB);
      tile_compute(kt, 0);
      if (has2) tile_compute(kt + 2, 1);
    }

    for (int off = 1; off < 16; off <<= 1)
      for (int r = 0; r < 4; ++r) lsum[r] += __shfl_xor(lsum[r], off);

    for (int ni = 0; ni < 4; ++ni) {
      const int col = h * 64 + ni * 16 + l15;
      for (int r = 0; r < 4; ++r) {
        const int row = q0 + w * 16 + quad * 4 + r;
        POp[(long)row * HID + col] = f2bf(acc_o[ni][r]);
      }
    }
    if (l15 == 0) {
      for (int r = 0; r < 4; ++r) {
        const int row = q0 + w * 16 + quad * 4 + r;
        PL[par * 32768 + row * 16 + h] = lsum[r];
      }
    }
  }
}

// O-projection GEMM with fused merge: A[m,k] = (PO0+PO1)[m,k] / (l0+l1)[m, k/64].
// BM=128 BN=64 BK=32, register-prefetch staging; raw partials prefetched during
// MFMA, merge VALU executed at ds_write time (where the vmcnt wait lands).
// Head of k-chunk kt*32 is kt>>1 (uniform per iteration). fp32 out + bf16 bias.
__global__ __launch_bounds__(256) void gemm_omerge(
    const short* __restrict__ PO0, const short* __restrict__ PO1,
    const float* __restrict__ PL,
    const short* __restrict__ W, const short* __restrict__ bia,
    float* __restrict__ C)
{
  constexpr int K = 1024;
  constexpr int N = 1024;
  __shared__ short As[128 * 32];
  __shared__ short Bs[64 * 32];

  const int t = threadIdx.x;
  const int w = t >> 6, lane = t & 63;
  const int l15 = lane & 15, quad = lane >> 4;
  const int wm = w >> 1, wn = w & 1;

  const int n0 = blockIdx.x * 64;
  const int m0 = blockIdx.y * 128;

  f32x4 acc[4][2];
  for (int mi = 0; mi < 4; ++mi)
    for (int ni = 0; ni < 2; ++ni)
      for (int r = 0; r < 4; ++r) acc[mi][ni][r] = 0.f;

  const int srow = t >> 2;        // 0..63
  const int sch  = (t & 3) * 8;
  const int r0 = m0 + srow, r1 = m0 + srow + 64;
  const long a0 = (long)r0 * K + sch;
  const long a1 = (long)r1 * K + sch;
  const short* Wp = W + (long)(n0 + srow) * K + sch;

  bf16x8 p00 = *(const bf16x8*)(PO0 + a0);
  bf16x8 p01 = *(const bf16x8*)(PO1 + a0);
  bf16x8 p10 = *(const bf16x8*)(PO0 + a1);
  bf16x8 p11 = *(const bf16x8*)(PO1 + a1);
  bf16x8 rb0 = *(const bf16x8*)(Wp);
  float il0 = 1.f / (PL[r0 * 16] + PL[32768 + r0 * 16]);
  float il1 = 1.f / (PL[r1 * 16] + PL[32768 + r1 * 16]);

  for (int kt = 0; kt < K / 32; ++kt) {
    __syncthreads();
    {
      bf16x8 m0v, m1v;
#pragma unroll
      for (int j = 0; j < 8; ++j) {
        m0v[j] = f2bf((bf2f(p00[j]) + bf2f(p01[j])) * il0);
        m1v[j] = f2bf((bf2f(p10[j]) + bf2f(p11[j])) * il1);
      }
      *(bf16x8*)&As[(srow)      * 32 + sch] = m0v;
      *(bf16x8*)&As[(srow + 64) * 32 + sch] = m1v;
      *(bf16x8*)&Bs[(srow)      * 32 + sch] = rb0;
    }
    __syncthreads();
    if (kt + 1 < K / 32) {  // prefetch next chunk (raw) + its inv factors
      const long kb = (long)(kt + 1) * 32;
      p00 = *(const bf16x8*)(PO0 + a0 + kb);
      p01 = *(const bf16x8*)(PO1 + a0 + kb);
      p10 = *(const bf16x8*)(PO0 + a1 + kb);
      p11 = *(const bf16x8*)(PO1 + a1 + kb);
      rb0 = *(const bf16x8*)(Wp + kb);
      const int hh = (kt + 1) >> 1;
      il0 = 1.f / (PL[r0 * 16 + hh] + PL[32768 + r0 * 16 + hh]);
      il1 = 1.f / (PL[r1 * 16 + hh] + PL[32768 + r1 * 16 + hh]);
    }
    bf16x8 af[4], bfr[2];
    for (int mi = 0; mi < 4; ++mi)
      af[mi] = *(const bf16x8*)&As[(wm * 64 + mi * 16 + l15) * 32 + quad * 8];
    for (int ni = 0; ni < 2; ++ni)
      bfr[ni] = *(const bf16x8*)&Bs[(wn * 32 + ni * 16 + l15) * 32 + quad * 8];
    for (int mi = 0; mi < 4; ++mi)
      for (int ni = 0; ni < 2; ++ni)
        acc[mi][ni] = __builtin_amdgcn_mfma_f32_16x16x32_bf16(af[mi], bfr[ni], acc[mi][ni], 0, 0, 0);
  }

  for (int ni = 0; ni < 2; ++ni) {
    const int col = n0 + wn * 32 + ni * 16 + l15;
    const float bv = bf2f(bia[col]);
    for (int mi = 0; mi < 4; ++mi) {
      const int row = m0 + wm * 64 + mi * 16 + quad * 4;
      for (int r = 0; r < 4; ++r)
        C[(long)(row + r) * N + col] = acc[mi][ni][r] + bv;
    }
  }
}

extern "C" void kernel_launch(void* const* d_in, const int* in_sizes, int n_in,
                              void* d_out, int out_size, void* d_ws, size_t ws_size,
                              hipStream_t stream) {
  constexpr long M1 = 1024L * 1024L;
  short* ws = (short*)d_ws;
  // dead-after-QKV region: xb, Wqb, Wkb, Wvb
  short* xb  = ws;              // 2M shorts
  short* Wqb = xb + 2 * M1;     // 1M
  short* Wkb = Wqb + M1;        // 1M
  short* Wvb = Wkb + M1;        // 1M
  // persistent: Wob, Qw, Kw, Vw, PO0 slot, small bf16 biases + cmw
  short* Wob = Wvb + M1;        // 1M
  short* Qw  = Wob + M1;        // 2M
  short* Kw  = Qw + 2 * M1;     // 2M
  short* Vw  = Kw + 2 * M1;     // 2M
  short* PO0 = Vw + 2 * M1;     // 2M
  short* bqb = PO0 + 2 * M1;    // 1024 each
  short* bkb = bqb + 1024;
  short* bvb = bkb + 1024;
  short* bob = bvb + 1024;
  short* cmb = bob + 1024;      // 16 (9 used)  -> total ~28MB + 10KB
  // partial aliases in dead region
  short* PO1 = xb;
  float* PL  = (float*)Wvb;     // 2*32768 floats = 256KB (within Wvb's 2MB)
  const int* modality = (const int*)d_in[11];

  convert10<<<dim3(256, 10), 256, 0, stream>>>(
      d_in[0], d_in[1], d_in[3], d_in[5], d_in[7],
      d_in[2], d_in[4], d_in[6], d_in[8], d_in[9],
      xb, Wqb, Wkb, Wvb, Wob, bqb, bkb, bvb, bob, cmb);

  // QKV projection: 3 mats x 16 n-tiles x 16 m-tiles = 768 blocks (prefetch staging)
  gemm_bt3<<<dim3(48, 16), 256, 0, stream>>>(
      xb, Wqb, Wkb, Wvb, bqb, bkb, bvb, Qw, Kw, Vw, 16);
  // attention: 16 pairs x 2 parities x 16 heads = 512 blocks
  attn_split<<<dim3(32, NHEAD), 256, 0, stream>>>(
      Qw, Kw, Vw, modality, cmb, PO0, PO1, PL);
  // output projection with fused merge: 256 blocks -> fp32 d_out
  gemm_omerge<<<dim3(16, 16), 256, 0, stream>>>(
      PO0, PO1, PL, Wob, bob, (float*)d_out);
}